// Round 11
// baseline (83.286 us; speedup 1.0000x reference)
//
#include <hip/hip_runtime.h>
#include <hip/hip_fp8.h>
#include <stdint.h>

#define N_CLS 8192
#define FEAT  512                           // elements; fp8 -> 512 B per row
#define BATCH 1024
#define NTI   32                            // 256-row tiles
#define NTJ   128                           // 64-col tiles
#define NBLK  2112                          // #{(i,j): j in [4i, 128)} = 8*264
#define NSLOT 4                             // FEAT/128 (K=128 per slot)
#define SLOTB 40960                         // bytes/slot: A 256*128 + B 64*128

typedef __attribute__((ext_vector_type(4))) float f32x4;
typedef __attribute__((ext_vector_type(2))) long longx2;

__device__ inline unsigned char f2fp8(float x) {
    __hip_fp8_e4m3 q(x);                    // OCP e4m3 (gfx950), HW convert
    return q.__x;
}

// ---------------- Kernel 1: sequential EMA per label -> fp8 protos ---------
__global__ __launch_bounds__(256) void ema_kernel(
    const float* __restrict__ features, const int* __restrict__ labels,
    const float* __restrict__ protos,
    unsigned char* __restrict__ Phi8, float* __restrict__ rowsum) {
    const int row  = blockIdx.x * 4 + (threadIdx.x >> 6);
    const int lane = threadIdx.x & 63;
    if (lane == 0) rowsum[row] = 0.f;

    float p[8];
    #pragma unroll
    for (int j = 0; j < 8; ++j) p[j] = protos[(size_t)row * FEAT + j * 64 + lane];

    for (int c = 0; c < BATCH / 64; ++c) {
        int lab = labels[c * 64 + lane];
        unsigned long long m = __ballot(lab == row);
        while (m) {
            int b = __builtin_ctzll(m);     // earliest remaining sample
            m &= m - 1;
            int s = c * 64 + b;
            float ss = 0.f;
            #pragma unroll
            for (int j = 0; j < 8; ++j) {
                float f = features[(size_t)s * FEAT + j * 64 + lane];
                p[j] = p[j] * 0.95f + f * 0.05f;
                ss += p[j] * p[j];
            }
            #pragma unroll
            for (int off = 32; off; off >>= 1) ss += __shfl_xor(ss, off);
            float inv = 1.0f / fmaxf(sqrtf(ss), 1e-12f);
            #pragma unroll
            for (int j = 0; j < 8; ++j) p[j] *= inv;
        }
    }
    #pragma unroll
    for (int j = 0; j < 8; ++j)
        Phi8[(size_t)row * FEAT + j * 64 + lane] = f2fp8(p[j]);
}

// ---------------- Kernel 2: 256x64 rect Gram tiles, fp8, K=128 slots -------
// 4 mega-slots, ring-2 (80 KB; 2 blocks/CU = exactly 160 KB). Slot body:
// STAGE(s+1) at top (latency hides under full slot), 12 ds_read_b128,
// 32 MFMA, vmcnt(0) own-staging drain + 1 barrier. 8-seg swizzle:
// read s = (h|(p<<2)) ^ x(r), x(r)=((r>>1)&3)|((r&1)<<2); store pre-swizzle
// (lane&7)^x(lane>>3). Every b128 = 2 lanes/bank (free); (h,p)->k map
// identical for A and B -> Gram correct for any HW k-order.
__global__ __launch_bounds__(512, 4) void gemm_disp_kernel(
    const unsigned char* __restrict__ Phi8, float* __restrict__ rowsum) {
    __shared__ __align__(16) char smem[2 * SLOTB];   // 80 KiB

    // XCD-aware swizzle (2112 = 8*264)
    int bid = blockIdx.x;
    int u = (bid & 7) * (NBLK / 8) + (bid >> 3);
    int i = 0;
    while (u >= NTJ - 4 * i) { u -= NTJ - 4 * i; ++i; }
    const int j = 4 * i + u;                // j >= 4i
    const bool diagovl = ((j >> 2) == i);   // col-range inside row-range

    const int w    = threadIdx.x >> 6;      // wave 0..7
    const int lane = threadIdx.x & 63;
    const int wr = w >> 1, wc = w & 1;      // 4x2 waves, 64x32 output each
    const int h = lane >> 4;                // k-group 0..3
    const int r = lane & 15;                // fragment row/col
    const int xr = ((r >> 1) & 3) | ((r & 1) << 2);
    const int s0 = (h ^ (xr & 3)) | (xr & 4);   // read seg, p=0 (p=1: ^4)

    const int Ibase = i * 256, Jbase = j * 64;

    f32x4 acc[4][2];
    #pragma unroll
    for (int m = 0; m < 4; ++m)
        #pragma unroll
        for (int n = 0; n < 2; ++n) acc[m][n] = (f32x4){0.f, 0.f, 0.f, 0.f};

    // staging: 5 loads/wave/slot. A (32 KB): 4 loads, rows w*32+c*8+(lane>>3);
    // B (8 KB): 1 load, rows w*8+(lane>>3). Source seg pre-swizzled.
    const int srr  = lane >> 3;             // row within 8-row chunk
    const int sseg = (lane & 7) ^ (((srr >> 1) & 3) | ((srr & 1) << 2));
    const unsigned char* gA =
        Phi8 + (size_t)(Ibase + w * 32 + srr) * FEAT + sseg * 16;
    const unsigned char* gB =
        Phi8 + (size_t)(Jbase + w * 8 + srr) * FEAT + sseg * 16;

#define STAGE(s)                                                              \
    {                                                                         \
        char* base = smem + ((s) & 1) * SLOTB;                                \
        _Pragma("unroll")                                                     \
        for (int c = 0; c < 4; ++c) {                                         \
            __builtin_amdgcn_global_load_lds(                                 \
                (const __attribute__((address_space(1))) void*)                \
                    (gA + (size_t)(c * 8) * FEAT + (s) * 128),                \
                (__attribute__((address_space(3))) void*)                     \
                    (base + w * 4096 + c * 1024), 16, 0, 0);                  \
        }                                                                     \
        __builtin_amdgcn_global_load_lds(                                     \
            (const __attribute__((address_space(1))) void*)(gB + (s) * 128),  \
            (__attribute__((address_space(3))) void*)                         \
                (base + 32768 + w * 1024), 16, 0, 0);                         \
    }

#define MFT(av, bv, mi, ni)                                                   \
    acc[mi][ni] = __builtin_amdgcn_mfma_f32_16x16x32_fp8_fp8(                 \
        av[0], bv[0], acc[mi][ni], 0, 0, 0);                                  \
    acc[mi][ni] = __builtin_amdgcn_mfma_f32_16x16x32_fp8_fp8(                 \
        av[1], bv[1], acc[mi][ni], 0, 0, 0);

#define SLOT(s, DO_STAGE, TAIL)                                               \
    {                                                                         \
        const char* As = smem + ((s) & 1) * SLOTB;                            \
        const char* Bs = As + 32768;                                          \
        if (DO_STAGE) STAGE((s) + 1)                                          \
        longx2 aL0, aL1, aL2, aL3, aH0, aH1, aH2, aH3, bL0, bL1, bH0, bH1;    \
        bL0 = *(const longx2*)(Bs + (wc * 32 +  0 + r) * 128 + s0 * 16);      \
        bH0 = *(const longx2*)(Bs + (wc * 32 +  0 + r) * 128 + (s0 ^ 4) * 16);\
        bL1 = *(const longx2*)(Bs + (wc * 32 + 16 + r) * 128 + s0 * 16);      \
        bH1 = *(const longx2*)(Bs + (wc * 32 + 16 + r) * 128 + (s0 ^ 4) * 16);\
        aL0 = *(const longx2*)(As + (wr * 64 +  0 + r) * 128 + s0 * 16);      \
        aH0 = *(const longx2*)(As + (wr * 64 +  0 + r) * 128 + (s0 ^ 4) * 16);\
        aL1 = *(const longx2*)(As + (wr * 64 + 16 + r) * 128 + s0 * 16);      \
        aH1 = *(const longx2*)(As + (wr * 64 + 16 + r) * 128 + (s0 ^ 4) * 16);\
        aL2 = *(const longx2*)(As + (wr * 64 + 32 + r) * 128 + s0 * 16);      \
        aH2 = *(const longx2*)(As + (wr * 64 + 32 + r) * 128 + (s0 ^ 4) * 16);\
        aL3 = *(const longx2*)(As + (wr * 64 + 48 + r) * 128 + s0 * 16);      \
        aH3 = *(const longx2*)(As + (wr * 64 + 48 + r) * 128 + (s0 ^ 4) * 16);\
        __builtin_amdgcn_s_setprio(1);                                        \
        MFT(aL0, bL0, 0, 0) MFT(aL1, bL0, 1, 0) MFT(aL2, bL0, 2, 0)           \
        MFT(aL3, bL0, 3, 0)                                                   \
        MFT(aL0, bL1, 0, 1) MFT(aL1, bL1, 1, 1) MFT(aL2, bL1, 2, 1)           \
        MFT(aL3, bL1, 3, 1)                                                   \
        MFT(aH0, bH0, 0, 0) MFT(aH1, bH0, 1, 0) MFT(aH2, bH0, 2, 0)           \
        MFT(aH3, bH0, 3, 0)                                                   \
        MFT(aH0, bH1, 0, 1) MFT(aH1, bH1, 1, 1) MFT(aH2, bH1, 2, 1)           \
        MFT(aH3, bH1, 3, 1)                                                   \
        __builtin_amdgcn_s_setprio(0);                                        \
        TAIL                                                                  \
    }

#define TAIL_SYNC                                                             \
    asm volatile("s_waitcnt vmcnt(0)" ::: "memory");                          \
    __builtin_amdgcn_s_barrier();
#define TAIL_NONE

    // prologue: stage slot 0, drain, publish
    STAGE(0)
    asm volatile("s_waitcnt vmcnt(0)" ::: "memory");
    __builtin_amdgcn_s_barrier();

    SLOT(0, 1, TAIL_SYNC)
    SLOT(1, 1, TAIL_SYNC)
    SLOT(2, 1, TAIL_SYNC)
    SLOT(3, 0, TAIL_NONE)

    // epilogue: e = exp(10*S); zero exact diagonal on overlap blocks
    // D layout: row = 4*h + q, col = r (HW-verified, dtype-independent)
    #pragma unroll
    for (int m = 0; m < 4; ++m)
        #pragma unroll
        for (int n = 0; n < 2; ++n)
            #pragma unroll
            for (int q = 0; q < 4; ++q) {
                float v = __expf(acc[m][n][q] * 10.0f);
                if (diagovl &&
                    (Ibase + wr * 64 + m * 16 + h * 4 + q) ==
                    (Jbase + wc * 32 + n * 16 + r))
                    v = 0.f;
                acc[m][n][q] = v;
            }

    // row credit (always): rowsum[Ibase + wr*64 + m*16 + 4h+q]
    #pragma unroll
    for (int m = 0; m < 4; ++m) {
        float rs[4];
        #pragma unroll
        for (int q = 0; q < 4; ++q)
            rs[q] = acc[m][0][q] + acc[m][1][q];
        #pragma unroll
        for (int q = 0; q < 4; ++q)
            #pragma unroll
            for (int off = 1; off < 16; off <<= 1) rs[q] += __shfl_xor(rs[q], off);
        if (r == 0) {
            #pragma unroll
            for (int q = 0; q < 4; ++q)
                atomicAdd(&rowsum[Ibase + wr * 64 + m * 16 + h * 4 + q], rs[q]);
        }
    }

    // col credit (only when mirror not computed elsewhere): j >= 4i+4
    if (!diagovl) {
        #pragma unroll
        for (int n = 0; n < 2; ++n) {
            float cs = 0.f;
            #pragma unroll
            for (int m = 0; m < 4; ++m)
                #pragma unroll
                for (int q = 0; q < 4; ++q) cs += acc[m][n][q];
            cs += __shfl_xor(cs, 16);
            cs += __shfl_xor(cs, 32);
            if (lane < 16)
                atomicAdd(&rowsum[Jbase + wc * 32 + n * 16 + r], cs);
        }
    }
}

// ---------------- Kernel 3: loss = mean(log(rowsum / (n-1))) ---------------
__global__ __launch_bounds__(512) void loss_kernel(
    const float* __restrict__ rowsum, float* __restrict__ out) {
    __shared__ float red[8];
    float s = 0.f;
    for (int i = threadIdx.x; i < N_CLS; i += 512)
        s += logf(rowsum[i] * (1.0f / (float)(N_CLS - 1)));
    #pragma unroll
    for (int off = 32; off; off >>= 1) s += __shfl_xor(s, off);
    if ((threadIdx.x & 63) == 0) red[threadIdx.x >> 6] = s;
    __syncthreads();
    if (threadIdx.x == 0) {
        float tot = 0.f;
        #pragma unroll
        for (int i = 0; i < 8; ++i) tot += red[i];
        out[0] = tot * (1.0f / (float)N_CLS);
    }
}

extern "C" void kernel_launch(void* const* d_in, const int* in_sizes, int n_in,
                              void* d_out, int out_size, void* d_ws, size_t ws_size,
                              hipStream_t stream) {
    (void)in_sizes; (void)n_in; (void)out_size; (void)ws_size;
    const float* features = (const float*)d_in[0];
    const int*   labels   = (const int*)d_in[1];
    const float* protos   = (const float*)d_in[2];
    float* out = (float*)d_out;

    unsigned char* Phi8 = (unsigned char*)d_ws;                     // 4 MiB
    float* rowsum = (float*)(Phi8 + (size_t)N_CLS * FEAT);          // 32 KiB

    ema_kernel<<<N_CLS / 4, 256, 0, stream>>>(features, labels, protos, Phi8, rowsum);
    gemm_disp_kernel<<<NBLK, 512, 0, stream>>>(Phi8, rowsum);
    loss_kernel<<<1, 512, 0, stream>>>(rowsum, out);
}